// Round 1
// 530.829 us; speedup vs baseline: 1.1281x; 1.1281x over previous
//
#include <hip/hip_runtime.h>

// Problem constants
#define BATCH 32
#define LP 1024
#define LQ 1024
#define LV 512
#define DIM 512

typedef __bf16 bf16x8 __attribute__((ext_vector_type(8)));
typedef float f32x4 __attribute__((ext_vector_type(4)));
typedef unsigned short ushort_t;
typedef unsigned short us8 __attribute__((ext_vector_type(8)));

// fp32 -> bf16 round-to-nearest-even (raw bits)
__device__ __forceinline__ ushort_t f2bf(float f) {
  unsigned int u = __float_as_uint(f);
  unsigned int r = (u + 0x7FFFu + ((u >> 16) & 1u)) >> 16;
  return (ushort_t)r;
}

__device__ __forceinline__ void async16(const void* g, void* l) {
  __builtin_amdgcn_global_load_lds(
      (const __attribute__((address_space(1))) unsigned int*)g,
      (__attribute__((address_space(3))) unsigned int*)l, 16, 0, 0);
}

// raw barrier: HW rendezvous + compiler memory fence, but NO vmcnt(0) drain
// (unlike __syncthreads) — this is what lets counted-vmcnt prefetch stay in
// flight across phases (T3/T4).
#define BARRIER() asm volatile("s_barrier" ::: "memory")
#define VMCNT(n) asm volatile("s_waitcnt vmcnt(" #n ")" ::: "memory")

// -------- plain fp32 -> bf16 convert (row-major copy), 8 elems/thread
__global__ __launch_bounds__(256)
void cvt_kernel(const float* __restrict__ in, ushort_t* __restrict__ out) {
  int i = blockIdx.x * blockDim.x + threadIdx.x;
  const float4* p = (const float4*)in;
  float4 a = p[i * 2], b = p[i * 2 + 1];
  us8 h;
  h[0] = f2bf(a.x); h[1] = f2bf(a.y); h[2] = f2bf(a.z); h[3] = f2bf(a.w);
  h[4] = f2bf(b.x); h[5] = f2bf(b.y); h[6] = f2bf(b.z); h[7] = f2bf(b.w);
  *(us8*)&out[(size_t)i * 8] = h;
}

// -------- transpose + convert: in [B][R][C] f32 -> outT [B][C][R] bf16, outR [B][R][C] bf16
__global__ void transpose_cvt(const float* __restrict__ in, ushort_t* __restrict__ outT,
                              ushort_t* __restrict__ outR, int R, int C) {
  __shared__ ushort_t tile[32][33];
  int b = blockIdx.z;
  int c0 = blockIdx.x * 32, r0 = blockIdx.y * 32;
  const float* inb = in + (size_t)b * R * C;
  ushort_t* outTb = outT + (size_t)b * R * C;
  ushort_t* outRb = outR + (size_t)b * R * C;
  int x = threadIdx.x, y = threadIdx.y;
#pragma unroll
  for (int k = 0; k < 4; ++k) {
    int r = r0 + y + k * 8;
    ushort_t h = f2bf(inb[(size_t)r * C + c0 + x]);
    tile[y + k * 8][x] = h;
    outRb[(size_t)r * C + c0 + x] = h;
  }
  __syncthreads();
#pragma unroll
  for (int k = 0; k < 4; ++k) {
    int c = c0 + y + k * 8;
    outTb[(size_t)c * R + r0 + x] = tile[x][y + k * 8];
  }
}

// MFMA cluster for one M-half (H=0/1): 4x4 fragments, one K-step of 32.
// setprio(1) around the cluster = T5 (requires the phase-split schedule).
template <int H>
__device__ __forceinline__ void mm8(f32x4 (&acc)[8][4], const bf16x8 (&af)[4],
                                    const bf16x8 (&bfv)[4]) {
  __builtin_amdgcn_s_setprio(1);
#pragma unroll
  for (int i = 0; i < 4; ++i)
#pragma unroll
    for (int j = 0; j < 4; ++j)
      acc[H * 4 + i][j] =
          __builtin_amdgcn_mfma_f32_16x16x32_bf16(af[i], bfv[j], acc[H * 4 + i][j], 0, 0, 0);
  __builtin_amdgcn_s_setprio(0);
}

// ============================================================================
// 256x256 tile, BK=64, 512 threads (8 waves, 2M x 4N), 8-phase counted-vmcnt
// schedule (T2+T3+T4+T5). LDS 128 KiB:
//   sA/sB = [2 dbuf][2 K-half][256 rows][32 cols] bf16  (16 KiB per K-half)
// Staging granularity = one K-half (16 wave-issues of global_load_lds x16B).
// K-halving makes in-place prefetch legal: a K-half's last ds_read phase ends
// >=1 barrier before its region is re-staged (see per-phase comments).
// st_16x32 swizzle: element e ^= ((e>>8)&1)<<4 (row&8 -> col^16), applied as
// inverse-permuted GLOBAL source on the write side (linear LDS dest, rule 21)
// and as a per-lane-constant col XOR on the ds_read side.
//
// MODE: 0 = plain f32 out; 1 = f32 out / lsumIn (+opt bf16 out2);
//       2 = score: P=exp(scale*acc) bf16 out + rowsum atomicAdd.
// ============================================================================
template <int MODE, bool OUT2>
__global__ __launch_bounds__(512, 2)
void gemm256(const ushort_t* __restrict__ A, const ushort_t* __restrict__ BT,
             const float* __restrict__ lsumIn, float* __restrict__ outF,
             ushort_t* __restrict__ outB, float* __restrict__ lsumOut,
             int M, int N, int K) {
  extern __shared__ ushort_t smem[];
  ushort_t* sA = smem;            // [2][2][256*32] = 32768 elems
  ushort_t* sB = smem + 32768;

  int b = blockIdx.z;
  int m0 = blockIdx.x * 256, n0 = blockIdx.y * 256;
  const ushort_t* Ab = A + ((size_t)b * M + m0) * K;
  const ushort_t* Bb = BT + ((size_t)b * N + n0) * K;
  int tid = threadIdx.x;
  int l = tid & 63, w = tid >> 6;
  int wm = w >> 2, wn = w & 3;          // wave tile: rows wm*128, cols wn*64
  int low = l & 15, quad = l >> 4;
  // read-side swizzle folds to a per-lane col XOR: frag rows have bit3 == l&8
  const int colsw = (quad * 8) ^ ((l & 8) ? 16 : 0);

  int NT = K >> 6;  // K-tiles of 64 (>= 8 for all our shapes)

  f32x4 acc[8][4];
  f32x4 zero = {0.f, 0.f, 0.f, 0.f};
#pragma unroll
  for (int i = 0; i < 8; ++i)
#pragma unroll
    for (int j = 0; j < 4; ++j) acc[i][j] = zero;

  // stage one K-half (256x32) of tile T into its dbuf slot. Linear LDS dest;
  // source chunk index inverse-swizzled (o^2 when l&32 -> col^16 when row&8).
  auto stageT = [&](const ushort_t* gb, ushort_t* sbase, int T, int kh) {
    ushort_t* hb = sbase + (((T & 1) << 1) + kh) * 8192;  // wave-uniform region
    int kc0 = (T << 6) + (kh << 5);
#pragma unroll
    for (int ii = 0; ii < 2; ++ii) {
      int o = w * 128 + ii * 64;  // wave-uniform chunk base (16B chunks)
      int ol = o + l;
      int cc = ((ol & 3) ^ ((l >> 4) & 2)) << 3;
      async16(gb + (size_t)(ol >> 2) * K + kc0 + cc, hb + o * 8);
    }
  };
  auto ldA = [&](bf16x8 (&af)[4], int buf, int k, int h) {
    const ushort_t* base = sA + ((buf << 1) + k) * 8192 + colsw;
    int r0 = wm * 128 + h * 64 + low;
#pragma unroll
    for (int i = 0; i < 4; ++i) af[i] = *(const bf16x8*)&base[(r0 + i * 16) * 32];
  };
  auto ldB = [&](bf16x8 (&bfv)[4], int buf, int k) {
    const ushort_t* base = sB + ((buf << 1) + k) * 8192 + colsw;
    int r0 = wn * 64 + low;
#pragma unroll
    for (int j = 0; j < 4; ++j) bfv[j] = *(const bf16x8*)&base[(r0 + j * 16) * 32];
  };

  // ---- prologue: tile0 (4 halves) + tile1 minus A-K1 (staged at ph1 of T=0)
  stageT(Ab, sA, 0, 0);
  stageT(Bb, sB, 0, 0);
  stageT(Ab, sA, 0, 1);
  stageT(Bb, sB, 0, 1);
  VMCNT(4);
  if (NT > 1) {
    stageT(Bb, sB, 1, 0);
    stageT(Ab, sA, 1, 0);
    stageT(Bb, sB, 1, 1);
    VMCNT(6);   // 14 issued/wave, <=6 outstanding => tile0's 8 landed
  } else {
    VMCNT(0);
  }
  BARRIER();

  bf16x8 af[4], bfv[4];
  for (int T = 0; T < NT; ++T) {
    int buf = T & 1;
    // ph1 (k0,h0): reads A-K0,B-K0(T). Stage A-K1(T+1) -> buf^1: its region
    // (tile T-1's A-K1) was last read in ph4(T-1), sealed by that barrier.
    ldB(bfv, buf, 0);
    ldA(af, buf, 0, 0);
    if (T + 1 < NT) stageT(Ab, sA, T + 1, 1);
    BARRIER();
    mm8<0>(acc, af, bfv);
    BARRIER();
    // ph2 (k0,h1): last reader of A-K0(T). Stage B-K0(T+2) -> CURRENT buf:
    // B-K0(T) was last read in ph1, sealed by ph1's trailing barrier.
    ldA(af, buf, 0, 1);
    if (T + 2 < NT) stageT(Bb, sB, T + 2, 0);
    BARRIER();
    mm8<1>(acc, af, bfv);
    BARRIER();
    // ph3 (k1,h0): reads A-K1,B-K1(T). Stage A-K0(T+2): last read ph2. Safe.
    ldB(bfv, buf, 1);
    ldA(af, buf, 1, 0);
    if (T + 2 < NT) stageT(Ab, sA, T + 2, 0);
    BARRIER();
    mm8<0>(acc, af, bfv);
    BARRIER();
    // ph4 (k1,h1): last reader of tile T. Stage B-K1(T+2): last read ph3.
    // Checkpoint: newest-3 halves are tile T+2's; vmcnt(6) => everything
    // tile T+1 needs (A-K1 @ph1 and older) has landed.
    ldA(af, buf, 1, 1);
    if (T + 2 < NT) stageT(Bb, sB, T + 2, 1);
    if (T + 1 < NT) {
      if (T + 2 < NT) { VMCNT(6); } else { VMCNT(0); }  // tail drain
    }
    BARRIER();
    mm8<1>(acc, af, bfv);
    BARRIER();
  }

  // ---- epilogue
  size_t ob = (size_t)b * M * N;
  if (MODE == 2) {
    const float sc = 0.04419417382415922f;  // 1/sqrt(512)
#pragma unroll
    for (int i = 0; i < 8; ++i) {
      int gr0 = m0 + wm * 128 + i * 16 + quad * 4;
#pragma unroll
      for (int r = 0; r < 4; ++r) {
        int gr = gr0 + r;
        float rs = 0.f;
#pragma unroll
        for (int j = 0; j < 4; ++j) {
          float p = __expf(acc[i][j][r] * sc);  // |scores| small: no max-sub
          rs += p;
          int gc = n0 + wn * 64 + j * 16 + low;
          outB[ob + (size_t)gr * N + gc] = f2bf(p);
        }
        rs += __shfl_xor(rs, 1);
        rs += __shfl_xor(rs, 2);
        rs += __shfl_xor(rs, 4);
        rs += __shfl_xor(rs, 8);
        if (low == 0) atomicAdd(&lsumOut[(size_t)b * M + gr], rs);
      }
    }
  } else {
#pragma unroll
    for (int i = 0; i < 8; ++i) {
      int gr0 = m0 + wm * 128 + i * 16 + quad * 4;
#pragma unroll
      for (int r = 0; r < 4; ++r) {
        int gr = gr0 + r;
        float inv = 1.f;
        if (MODE == 1) inv = 1.f / lsumIn[(size_t)b * M + gr];
#pragma unroll
        for (int j = 0; j < 4; ++j) {
          int gc = n0 + wn * 64 + j * 16 + low;
          float o = acc[i][j][r] * inv;
          outF[ob + (size_t)gr * N + gc] = o;
          if (OUT2) outB[ob + (size_t)gr * N + gc] = f2bf(o);
        }
      }
    }
  }
}

#define LDS_BYTES 131072

extern "C" void kernel_launch(void* const* d_in, const int* in_sizes, int n_in,
                              void* d_out, int out_size, void* d_ws, size_t ws_size,
                              hipStream_t stream) {
  (void)in_sizes; (void)n_in; (void)out_size; (void)ws_size;
  const float* pre = (const float*)d_in[0];
  const float* q   = (const float*)d_in[1];
  const float* v   = (const float*)d_in[2];

  float* out      = (float*)d_out;
  float* wc       = out;                                   // weightedContext [B][LQ][DIM]
  float* energy   = out + (size_t)BATCH * LQ * DIM;        // energy          [B][LQ][DIM]
  float* precomp  = out + 2 * (size_t)BATCH * LQ * DIM;    // precompute      [B][LP][DIM]

  char* ws = (char*)d_ws;
  size_t off = 0;
  auto alloc = [&](size_t bytes) {
    void* p = ws + off;
    off += (bytes + 255) & ~(size_t)255;
    return p;
  };
  ushort_t* preB = (ushort_t*)alloc((size_t)BATCH * LP * DIM * 2);
  ushort_t* qB   = (ushort_t*)alloc((size_t)BATCH * LQ * DIM * 2);
  ushort_t* vB   = (ushort_t*)alloc((size_t)BATCH * LV * DIM * 2);
  ushort_t* qT   = (ushort_t*)alloc((size_t)BATCH * DIM * LQ * 2);
  ushort_t* vT   = (ushort_t*)alloc((size_t)BATCH * DIM * LV * 2);
  ushort_t* Pp   = (ushort_t*)alloc((size_t)BATCH * LP * LQ * 2);
  ushort_t* Pe   = (ushort_t*)alloc((size_t)BATCH * LQ * LV * 2);
  ushort_t* Ebf  = (ushort_t*)alloc((size_t)BATCH * LQ * DIM * 2);
  float* lp = (float*)alloc((size_t)BATCH * LP * 4);
  float* le = (float*)alloc((size_t)BATCH * LQ * 4);

  static bool attr_done = false;
  if (!attr_done) {
    attr_done = true;
    hipFuncSetAttribute(reinterpret_cast<const void*>(&gemm256<2, false>),
                        hipFuncAttributeMaxDynamicSharedMemorySize, LDS_BYTES);
    hipFuncSetAttribute(reinterpret_cast<const void*>(&gemm256<1, false>),
                        hipFuncAttributeMaxDynamicSharedMemorySize, LDS_BYTES);
    hipFuncSetAttribute(reinterpret_cast<const void*>(&gemm256<1, true>),
                        hipFuncAttributeMaxDynamicSharedMemorySize, LDS_BYTES);
    hipFuncSetAttribute(reinterpret_cast<const void*>(&gemm256<0, false>),
                        hipFuncAttributeMaxDynamicSharedMemorySize, LDS_BYTES);
  }

  hipMemsetAsync(lp, 0, (size_t)BATCH * (LP + LQ) * 4, stream);

  // prep: bf16 copies (+transposes for the PV gemms)
  cvt_kernel<<<(size_t)BATCH * LP * DIM / 8 / 256, 256, 0, stream>>>(pre, preB);
  transpose_cvt<<<dim3(DIM / 32, LQ / 32, BATCH), dim3(32, 8), 0, stream>>>(q, qT, qB, LQ, DIM);
  transpose_cvt<<<dim3(DIM / 32, LV / 32, BATCH), dim3(32, 8), 0, stream>>>(v, vT, vB, LV, DIM);

  // stream1 scores: Pp = exp(sc * pre.q^T)  [B][LP][LQ]
  gemm256<2, false><<<dim3(LP / 256, LQ / 256, BATCH), 512, LDS_BYTES, stream>>>(
      preB, qB, nullptr, nullptr, Pp, lp, LP, LQ, DIM);
  // stream2 scores: Pe = exp(sc * q.v^T)    [B][LQ][LV]
  gemm256<2, false><<<dim3(LQ / 256, LV / 256, BATCH), 512, LDS_BYTES, stream>>>(
      qB, vB, nullptr, nullptr, Pe, le, LQ, LV, DIM);

  // precompute = (Pp . q) / lp   : A=Pp [LP][LQ], BT=qT [DIM][LQ]
  gemm256<1, false><<<dim3(LP / 256, DIM / 256, BATCH), 512, LDS_BYTES, stream>>>(
      Pp, qT, lp, precomp, nullptr, nullptr, LP, DIM, LQ);
  // energy = (Pe . v) / le       : A=Pe [LQ][LV], BT=vT [DIM][LV]; also bf16 copy
  gemm256<1, true><<<dim3(LQ / 256, DIM / 256, BATCH), 512, LDS_BYTES, stream>>>(
      Pe, vT, le, energy, Ebf, nullptr, LQ, DIM, LV);
  // weightedContext = Ebf . v    : A=Ebf [LQ][DIM], BT=vT [DIM][LV]
  gemm256<0, false><<<dim3(LQ / 256, DIM / 256, BATCH), 512, LDS_BYTES, stream>>>(
      Ebf, vT, nullptr, wc, nullptr, nullptr, LQ, DIM, LV);
}

// Round 2
// 505.000 us; speedup vs baseline: 1.1858x; 1.0511x over previous
//
#include <hip/hip_runtime.h>

// Problem constants
#define BATCH 32
#define LP 1024
#define LQ 1024
#define LV 512
#define DIM 512

typedef __bf16 bf16x8 __attribute__((ext_vector_type(8)));
typedef float f32x4 __attribute__((ext_vector_type(4)));
typedef unsigned short ushort_t;
typedef unsigned short us8 __attribute__((ext_vector_type(8)));
typedef unsigned short us4 __attribute__((ext_vector_type(4)));

// fp32 -> bf16 round-to-nearest-even (raw bits)
__device__ __forceinline__ ushort_t f2bf(float f) {
  unsigned int u = __float_as_uint(f);
  unsigned int r = (u + 0x7FFFu + ((u >> 16) & 1u)) >> 16;
  return (ushort_t)r;
}

__device__ __forceinline__ void async16(const void* g, void* l) {
  __builtin_amdgcn_global_load_lds(
      (const __attribute__((address_space(1))) unsigned int*)g,
      (__attribute__((address_space(3))) unsigned int*)l, 16, 0, 0);
}

// raw barrier: HW rendezvous + compiler memory fence, but NO vmcnt(0) drain.
#define BARRIER() asm volatile("s_barrier" ::: "memory")
#define VMCNT(n) asm volatile("s_waitcnt vmcnt(" #n ")" ::: "memory")

// ============================================================================
// Fused prep: one launch, three segments.
//  seg0 (fid < 8192):       pre f32 -> preB bf16 row-major (float4 -> us8)
//  seg1 (8192 <= fid<12288): q -> qB (row-major) + qT (transposed), 64x64 tiles
//  seg2 (fid >= 12288):      v -> vB + vT
// All global loads float4 (16B), stores us4 (8B) / us8 (16B).
// ============================================================================
__global__ __launch_bounds__(256)
void prep_kernel(const float* __restrict__ pre, const float* __restrict__ q,
                 const float* __restrict__ v, ushort_t* __restrict__ preB,
                 ushort_t* __restrict__ qB, ushort_t* __restrict__ vB,
                 ushort_t* __restrict__ qT, ushort_t* __restrict__ vT) {
  __shared__ ushort_t tile[64][68];  // +4 pad: 8B-aligned rows, conflict-light
  int fid = blockIdx.x, tid = threadIdx.x;

  if (fid < 8192) {  // ---- cvt pre (8 elems/thread)
    size_t i = (size_t)fid * 256 + tid;
    const float4* p = (const float4*)pre;
    float4 a = p[i * 2], b = p[i * 2 + 1];
    us8 h;
    h[0] = f2bf(a.x); h[1] = f2bf(a.y); h[2] = f2bf(a.z); h[3] = f2bf(a.w);
    h[4] = f2bf(b.x); h[5] = f2bf(b.y); h[6] = f2bf(b.z); h[7] = f2bf(b.w);
    *(us8*)&preB[i * 8] = h;
    return;
  }

  int lid; const float* in; ushort_t* oT; ushort_t* oR; int R;
  if (fid < 12288) { lid = fid - 8192;  in = q; oT = qT; oR = qB; R = LQ; }
  else             { lid = fid - 12288; in = v; oT = vT; oR = vB; R = LV; }
  int tiles = (R / 64) * (DIM / 64);
  int b = lid / tiles, t = lid % tiles;
  int r0 = (t / (DIM / 64)) * 64, c0 = (t % (DIM / 64)) * 64;
  const float* ib = in + (size_t)b * R * DIM;
  ushort_t* oRb = oR + (size_t)b * R * DIM;
  ushort_t* oTb = oT + (size_t)b * R * DIM;  // [DIM][R]

  int rr = tid >> 4, c4 = (tid & 15) << 2;
#pragma unroll
  for (int k = 0; k < 4; ++k) {
    int r = rr + k * 16;
    float4 f = *(const float4*)&ib[(size_t)(r0 + r) * DIM + c0 + c4];
    us4 o;
    o[0] = f2bf(f.x); o[1] = f2bf(f.y); o[2] = f2bf(f.z); o[3] = f2bf(f.w);
    *(us4*)&tile[r][c4] = o;
    *(us4*)&oRb[(size_t)(r0 + r) * DIM + c0 + c4] = o;
  }
  __syncthreads();
#pragma unroll
  for (int j = 0; j < 2; ++j) {
    int idx = tid + 256 * j;
    int c = idx >> 3, r8 = (idx & 7) << 3;
    us8 o;
#pragma unroll
    for (int i = 0; i < 8; ++i) o[i] = tile[r8 + i][c];
    *(us8*)&oTb[(size_t)(c0 + c) * R + r0 + r8] = o;  // outT[col][row]
  }
}

// MFMA cluster for one M-half (H=0/1): 4x4 fragments, one K-step of 32. (T5)
template <int H>
__device__ __forceinline__ void mm8(f32x4 (&acc)[8][4], const bf16x8 (&af)[4],
                                    const bf16x8 (&bfv)[4]) {
  __builtin_amdgcn_s_setprio(1);
#pragma unroll
  for (int i = 0; i < 4; ++i)
#pragma unroll
    for (int j = 0; j < 4; ++j)
      acc[H * 4 + i][j] =
          __builtin_amdgcn_mfma_f32_16x16x32_bf16(af[i], bfv[j], acc[H * 4 + i][j], 0, 0, 0);
  __builtin_amdgcn_s_setprio(0);
}

// Per-segment GEMM parameters (runtime; lets independent GEMMs share a launch).
struct GSeg {
  const ushort_t* A;       // [B][M][K] bf16
  const ushort_t* BT;      // [B][N][K] bf16
  const float* lsumIn;     // row divisor (mode 1) or null
  float* outF;             // f32 out (mode 0/1)
  ushort_t* outB;          // bf16 out (mode 2 = P; mode 1 optional copy)
  float* lsumOut;          // row-sum atomics (mode 2)
  int M, N, K, gx, gy, nblk, mode;
};

// ============================================================================
// 256x256 tile, BK=64, 512 threads (8 waves, 2M x 4N), 8-phase counted-vmcnt
// schedule (T2+T3+T4+T5) — core schedule identical to the verified round-1
// kernel. New: 1D grid, two runtime segments per launch, per-segment bijective
// XCD chunked swizzle (T1) so consecutive work-ids (panel sharers) land on
// the same XCD L2.
// ============================================================================
__global__ __launch_bounds__(512, 2)
void gemm256d(GSeg s0, GSeg s1, int split) {
  extern __shared__ ushort_t smem[];
  ushort_t* sA = smem;            // [2][2][256*32] = 32768 elems
  ushort_t* sB = smem + 32768;

  int fid = blockIdx.x;
  bool second = fid >= split;
  GSeg s = second ? s1 : s0;
  int lid = second ? fid - split : fid;
  // T1: chunked bijective XCD swizzle (nblk divisible by 8 for all segments)
  int cpx = s.nblk >> 3;
  int swz = (lid & 7) * cpx + (lid >> 3);
  int x = swz % s.gx;
  int t = swz / s.gx;
  int y = t % s.gy;
  int b = t / s.gy;

  int m0 = x * 256, n0 = y * 256;
  const ushort_t* Ab = s.A + ((size_t)b * s.M + m0) * s.K;
  const ushort_t* Bb = s.BT + ((size_t)b * s.N + n0) * s.K;
  int tid = threadIdx.x;
  int l = tid & 63, w = tid >> 6;
  int wm = w >> 2, wn = w & 3;          // wave tile: rows wm*128, cols wn*64
  int low = l & 15, quad = l >> 4;
  // read-side st_16x32 swizzle folds to a per-lane col XOR (frag row bit3 = l&8)
  const int colsw = (quad * 8) ^ ((l & 8) ? 16 : 0);
  const int K = s.K;
  int NT = K >> 6;  // K-tiles of 64

  f32x4 acc[8][4];
  f32x4 zero = {0.f, 0.f, 0.f, 0.f};
#pragma unroll
  for (int i = 0; i < 8; ++i)
#pragma unroll
    for (int j = 0; j < 4; ++j) acc[i][j] = zero;

  // stage one K-half (256x32) of tile T into its dbuf slot. Linear LDS dest;
  // source chunk index inverse-swizzled (row&8 -> chunk^2).
  auto stageT = [&](const ushort_t* gb, ushort_t* sbase, int T, int kh) {
    ushort_t* hb = sbase + (((T & 1) << 1) + kh) * 8192;  // wave-uniform region
    int kc0 = (T << 6) + (kh << 5);
#pragma unroll
    for (int ii = 0; ii < 2; ++ii) {
      int o = w * 128 + ii * 64;  // wave-uniform chunk base (16B chunks)
      int ol = o + l;
      int cc = ((ol & 3) ^ ((l >> 4) & 2)) << 3;
      async16(gb + (size_t)(ol >> 2) * K + kc0 + cc, hb + o * 8);
    }
  };
  auto ldA = [&](bf16x8 (&af)[4], int buf, int k, int h) {
    const ushort_t* base = sA + ((buf << 1) + k) * 8192 + colsw;
    int r0 = wm * 128 + h * 64 + low;
#pragma unroll
    for (int i = 0; i < 4; ++i) af[i] = *(const bf16x8*)&base[(r0 + i * 16) * 32];
  };
  auto ldB = [&](bf16x8 (&bfv)[4], int buf, int k) {
    const ushort_t* base = sB + ((buf << 1) + k) * 8192 + colsw;
    int r0 = wn * 64 + low;
#pragma unroll
    for (int j = 0; j < 4; ++j) bfv[j] = *(const bf16x8*)&base[(r0 + j * 16) * 32];
  };

  // ---- prologue: tile0 (4 halves) + tile1 minus A-K1 (staged at ph1 of T=0)
  stageT(Ab, sA, 0, 0);
  stageT(Bb, sB, 0, 0);
  stageT(Ab, sA, 0, 1);
  stageT(Bb, sB, 0, 1);
  VMCNT(4);
  if (NT > 1) {
    stageT(Bb, sB, 1, 0);
    stageT(Ab, sA, 1, 0);
    stageT(Bb, sB, 1, 1);
    VMCNT(6);   // 14 issued/wave, <=6 outstanding => tile0's 8 landed
  } else {
    VMCNT(0);
  }
  BARRIER();

  bf16x8 af[4], bfv[4];
  for (int T = 0; T < NT; ++T) {
    int buf = T & 1;
    // ph1 (k0,h0). Stage A-K1(T+1) -> buf^1 (region sealed at ph4(T-1)).
    ldB(bfv, buf, 0);
    ldA(af, buf, 0, 0);
    if (T + 1 < NT) stageT(Ab, sA, T + 1, 1);
    BARRIER();
    mm8<0>(acc, af, bfv);
    BARRIER();
    // ph2 (k0,h1): last reader of A-K0(T). Stage B-K0(T+2) (sealed @ph1).
    ldA(af, buf, 0, 1);
    if (T + 2 < NT) stageT(Bb, sB, T + 2, 0);
    BARRIER();
    mm8<1>(acc, af, bfv);
    BARRIER();
    // ph3 (k1,h0). Stage A-K0(T+2) (sealed @ph2).
    ldB(bfv, buf, 1);
    ldA(af, buf, 1, 0);
    if (T + 2 < NT) stageT(Ab, sA, T + 2, 0);
    BARRIER();
    mm8<0>(acc, af, bfv);
    BARRIER();
    // ph4 (k1,h1): last reader of tile T. Stage B-K1(T+2) (sealed @ph3).
    // vmcnt(6): newest-3 halves are tile T+2's => tile T+1 fully landed.
    ldA(af, buf, 1, 1);
    if (T + 2 < NT) stageT(Bb, sB, T + 2, 1);
    if (T + 1 < NT) {
      if (T + 2 < NT) { VMCNT(6); } else { VMCNT(0); }  // tail drain
    }
    BARRIER();
    mm8<1>(acc, af, bfv);
    BARRIER();
  }

  // ---- epilogue (runtime mode; uniform branches)
  size_t ob = (size_t)b * s.M * s.N;
  if (s.mode == 2) {
    const float sc = 0.04419417382415922f;  // 1/sqrt(512)
#pragma unroll
    for (int i = 0; i < 8; ++i) {
      int gr0 = m0 + wm * 128 + i * 16 + quad * 4;
#pragma unroll
      for (int r = 0; r < 4; ++r) {
        int gr = gr0 + r;
        float rs = 0.f;
#pragma unroll
        for (int j = 0; j < 4; ++j) {
          float p = __expf(acc[i][j][r] * sc);  // |scores| small: no max-sub
          rs += p;
          int gc = n0 + wn * 64 + j * 16 + low;
          s.outB[ob + (size_t)gr * s.N + gc] = f2bf(p);
        }
        rs += __shfl_xor(rs, 1);
        rs += __shfl_xor(rs, 2);
        rs += __shfl_xor(rs, 4);
        rs += __shfl_xor(rs, 8);
        if (low == 0) atomicAdd(&s.lsumOut[(size_t)b * s.M + gr], rs);
      }
    }
  } else {
#pragma unroll
    for (int i = 0; i < 8; ++i) {
      int gr0 = m0 + wm * 128 + i * 16 + quad * 4;
#pragma unroll
      for (int r = 0; r < 4; ++r) {
        int gr = gr0 + r;
        float inv = 1.f;
        if (s.lsumIn) inv = 1.f / s.lsumIn[(size_t)b * s.M + gr];
#pragma unroll
        for (int j = 0; j < 4; ++j) {
          int gc = n0 + wn * 64 + j * 16 + low;
          float o = acc[i][j][r] * inv;
          s.outF[ob + (size_t)gr * s.N + gc] = o;
          if (s.outB) s.outB[ob + (size_t)gr * s.N + gc] = f2bf(o);
        }
      }
    }
  }
}

#define LDS_BYTES 131072

extern "C" void kernel_launch(void* const* d_in, const int* in_sizes, int n_in,
                              void* d_out, int out_size, void* d_ws, size_t ws_size,
                              hipStream_t stream) {
  (void)in_sizes; (void)n_in; (void)out_size; (void)ws_size;
  const float* pre = (const float*)d_in[0];
  const float* q   = (const float*)d_in[1];
  const float* v   = (const float*)d_in[2];

  float* out      = (float*)d_out;
  float* wc       = out;                                   // weightedContext [B][LQ][DIM]
  float* energy   = out + (size_t)BATCH * LQ * DIM;        // energy          [B][LQ][DIM]
  float* precomp  = out + 2 * (size_t)BATCH * LQ * DIM;    // precompute      [B][LP][DIM]

  char* ws = (char*)d_ws;
  size_t off = 0;
  auto alloc = [&](size_t bytes) {
    void* p = ws + off;
    off += (bytes + 255) & ~(size_t)255;
    return p;
  };
  ushort_t* preB = (ushort_t*)alloc((size_t)BATCH * LP * DIM * 2);
  ushort_t* qB   = (ushort_t*)alloc((size_t)BATCH * LQ * DIM * 2);
  ushort_t* vB   = (ushort_t*)alloc((size_t)BATCH * LV * DIM * 2);
  ushort_t* qT   = (ushort_t*)alloc((size_t)BATCH * DIM * LQ * 2);
  ushort_t* vT   = (ushort_t*)alloc((size_t)BATCH * DIM * LV * 2);
  ushort_t* Pp   = (ushort_t*)alloc((size_t)BATCH * LP * LQ * 2);
  ushort_t* Pe   = (ushort_t*)alloc((size_t)BATCH * LQ * LV * 2);
  ushort_t* Ebf  = (ushort_t*)alloc((size_t)BATCH * LQ * DIM * 2);
  float* lp = (float*)alloc((size_t)BATCH * LP * 4);
  float* le = (float*)alloc((size_t)BATCH * LQ * 4);

  static bool attr_done = false;
  if (!attr_done) {
    attr_done = true;
    hipFuncSetAttribute(reinterpret_cast<const void*>(&gemm256d),
                        hipFuncAttributeMaxDynamicSharedMemorySize, LDS_BYTES);
  }

  hipMemsetAsync(lp, 0, (size_t)BATCH * (LP + LQ) * 4, stream);

  // prep: one launch (pre cvt + q/v transpose-cvt), all accesses vectorized
  prep_kernel<<<8192 + 4096 + 2048, 256, 0, stream>>>(pre, q, v, preB, qB, vB, qT, vT);

  // scores: Pp = exp(sc*pre.q^T) [B][LP][LQ]; Pe = exp(sc*q.v^T) [B][LQ][LV]
  GSeg sc1 = {preB, qB, nullptr, nullptr, Pp, lp, LP, LQ, DIM, LP / 256, LQ / 256,
              (LP / 256) * (LQ / 256) * BATCH, 2};
  GSeg sc2 = {qB, vB, nullptr, nullptr, Pe, le, LQ, LV, DIM, LQ / 256, LV / 256,
              (LQ / 256) * (LV / 256) * BATCH, 2};
  gemm256d<<<sc1.nblk + sc2.nblk, 512, LDS_BYTES, stream>>>(sc1, sc2, sc1.nblk);

  // pv: precompute = (Pp.q)/lp ; energy = (Pe.v)/le (+bf16 copy Ebf)
  GSeg pv1 = {Pp, qT, lp, precomp, nullptr, nullptr, LP, DIM, LQ, LP / 256, DIM / 256,
              (LP / 256) * (DIM / 256) * BATCH, 1};
  GSeg pv2 = {Pe, vT, le, energy, Ebf, nullptr, LQ, DIM, LV, LQ / 256, DIM / 256,
              (LQ / 256) * (DIM / 256) * BATCH, 1};
  gemm256d<<<pv1.nblk + pv2.nblk, 512, LDS_BYTES, stream>>>(pv1, pv2, pv1.nblk);

  // weightedContext = Ebf . v
  GSeg wcs = {Ebf, vT, nullptr, wc, nullptr, nullptr, LQ, DIM, LV, LQ / 256, DIM / 256,
              (LQ / 256) * (DIM / 256) * BATCH, 0};
  gemm256d<<<wcs.nblk, 512, LDS_BYTES, stream>>>(wcs, wcs, wcs.nblk);
}

// Round 3
// 499.596 us; speedup vs baseline: 1.1986x; 1.0108x over previous
//
#include <hip/hip_runtime.h>

// Problem constants
#define BATCH 32
#define LP 1024
#define LQ 1024
#define LV 512
#define DIM 512

typedef __bf16 bf16x8 __attribute__((ext_vector_type(8)));
typedef float f32x4 __attribute__((ext_vector_type(4)));
typedef unsigned short ushort_t;
typedef unsigned short us8 __attribute__((ext_vector_type(8)));
typedef unsigned short us4 __attribute__((ext_vector_type(4)));

// fp32 -> bf16 round-to-nearest-even (raw bits)
__device__ __forceinline__ ushort_t f2bf(float f) {
  unsigned int u = __float_as_uint(f);
  unsigned int r = (u + 0x7FFFu + ((u >> 16) & 1u)) >> 16;
  return (ushort_t)r;
}

__device__ __forceinline__ void async16(const void* g, void* l) {
  __builtin_amdgcn_global_load_lds(
      (const __attribute__((address_space(1))) unsigned int*)g,
      (__attribute__((address_space(3))) unsigned int*)l, 16, 0, 0);
}

// raw barrier: HW rendezvous + compiler memory fence, but NO vmcnt(0) drain.
#define BARRIER() asm volatile("s_barrier" ::: "memory")
#define VMCNT(n) asm volatile("s_waitcnt vmcnt(" #n ")" ::: "memory")

// ============================================================================
// Fused prep: one launch, four segments.
//  seg0 (fid < 8192):   pre f32 -> preB bf16 row-major (2x float4 -> us8)
//  seg1 (< 8256):       zero lp/le row-sum buffers (replaces hipMemsetAsync)
//  seg2 (< 12352):      q -> qB (row-major) + qT (transposed), 64x64 tiles
//  seg3 (rest):         v -> vB + vT
// Transpose trick: pack bf16 of two ADJACENT rows into one u32 at write time;
// LDS tile is [col][row-pair] u32 with stride 33 (<=2-way banks both sides).
// Reading 8 consecutive u32 of a column yields 16 bf16 already in transposed
// linear order (u32 k = rows 2k,2k+1) -> two 16B global stores, no repack.
// ============================================================================
__global__ __launch_bounds__(256)
void prep_kernel(const float* __restrict__ pre, const float* __restrict__ q,
                 const float* __restrict__ v, ushort_t* __restrict__ preB,
                 ushort_t* __restrict__ qB, ushort_t* __restrict__ vB,
                 ushort_t* __restrict__ qT, ushort_t* __restrict__ vT,
                 float* __restrict__ zbase) {
  __shared__ unsigned int T[64][33];
  int fid = blockIdx.x, tid = threadIdx.x;

  if (fid < 8192) {  // ---- cvt pre (8 elems/thread)
    size_t i = (size_t)fid * 256 + tid;
    const float4* p = (const float4*)pre;
    float4 a = p[i * 2], b = p[i * 2 + 1];
    us8 h;
    h[0] = f2bf(a.x); h[1] = f2bf(a.y); h[2] = f2bf(a.z); h[3] = f2bf(a.w);
    h[4] = f2bf(b.x); h[5] = f2bf(b.y); h[6] = f2bf(b.z); h[7] = f2bf(b.w);
    *(us8*)&preB[i * 8] = h;
    return;
  }
  if (fid < 8256) {  // ---- zero lp+le (contiguous 256 KiB)
    int i = (fid - 8192) * 256 + tid;
    ((float4*)zbase)[i] = make_float4(0.f, 0.f, 0.f, 0.f);
    return;
  }

  int lid = fid - 8256;
  const float* in; ushort_t* oT; ushort_t* oR; int R;
  if (lid < 4096) { in = q; oT = qT; oR = qB; R = LQ; }
  else            { lid -= 4096; in = v; oT = vT; oR = vB; R = LV; }
  int tpb = (R / 64) * (DIM / 64);
  int b = lid / tpb, t = lid % tpb;
  int r0 = (t / (DIM / 64)) * 64, c0 = (t % (DIM / 64)) * 64;
  const float* ib = in + (size_t)b * R * DIM;
  ushort_t* oRb = oR + (size_t)b * R * DIM;
  ushort_t* oTb = oT + (size_t)b * R * DIM;  // [DIM][R]

  int a = tid >> 4, c4 = (tid & 15) * 4;
#pragma unroll
  for (int p = 0; p < 2; ++p) {
    int rp = a + p * 16;          // row-pair index 0..31
    int r = r0 + rp * 2;
    float4 f0 = *(const float4*)&ib[(size_t)r * DIM + c0 + c4];
    float4 f1 = *(const float4*)&ib[(size_t)(r + 1) * DIM + c0 + c4];
    ushort_t h0[4] = {f2bf(f0.x), f2bf(f0.y), f2bf(f0.z), f2bf(f0.w)};
    ushort_t h1[4] = {f2bf(f1.x), f2bf(f1.y), f2bf(f1.z), f2bf(f1.w)};
#pragma unroll
    for (int j = 0; j < 4; ++j)
      T[c4 + j][rp] = (unsigned)h0[j] | ((unsigned)h1[j] << 16);
    us4 s0 = {h0[0], h0[1], h0[2], h0[3]};
    us4 s1 = {h1[0], h1[1], h1[2], h1[3]};
    *(us4*)&oRb[(size_t)r * DIM + c0 + c4] = s0;
    *(us4*)&oRb[(size_t)(r + 1) * DIM + c0 + c4] = s1;
  }
  __syncthreads();
  int c = tid >> 2, sg = tid & 3;
  unsigned int u[8];
#pragma unroll
  for (int i = 0; i < 8; ++i) u[i] = T[c][sg * 8 + i];
  uint4 lo = {u[0], u[1], u[2], u[3]}, hi = {u[4], u[5], u[6], u[7]};
  *(uint4*)&oTb[(size_t)(c0 + c) * R + r0 + sg * 16] = lo;
  *(uint4*)&oTb[(size_t)(c0 + c) * R + r0 + sg * 16 + 8] = hi;
}

// MFMA cluster for one M-half (H=0/1): 4x4 fragments, one K-step of 32. (T5)
template <int H>
__device__ __forceinline__ void mm8(f32x4 (&acc)[8][4], const bf16x8 (&af)[4],
                                    const bf16x8 (&bfv)[4]) {
  __builtin_amdgcn_s_setprio(1);
#pragma unroll
  for (int i = 0; i < 4; ++i)
#pragma unroll
    for (int j = 0; j < 4; ++j)
      acc[H * 4 + i][j] =
          __builtin_amdgcn_mfma_f32_16x16x32_bf16(af[i], bfv[j], acc[H * 4 + i][j], 0, 0, 0);
  __builtin_amdgcn_s_setprio(0);
}

// Per-segment GEMM parameters (runtime; lets independent GEMMs share a launch).
struct GSeg {
  const ushort_t* A;       // [B][M][K] bf16
  const ushort_t* BT;      // [B][N][K] bf16
  const float* lsumIn;     // row divisor (mode 1) or null
  float* outF;             // f32 out (mode 0/1)
  ushort_t* outB;          // bf16 out (mode 2 = P; mode 1 optional copy)
  float* lsumOut;          // row-sum atomics (mode 2)
  int M, N, K, gx, gy, nblk, mode;
};

// ============================================================================
// 256x256 tile, BK=64, 512 threads (8 waves, 2M x 4N), 8-phase counted-vmcnt
// schedule (T2+T3+T4+T5) — core schedule identical to the verified round-1/2
// kernel. 1D grid, two runtime segments per launch, per-segment bijective
// XCD chunked swizzle (T1).
// ============================================================================
__global__ __launch_bounds__(512, 2)
void gemm256d(GSeg s0, GSeg s1, int split) {
  extern __shared__ ushort_t smem[];
  ushort_t* sA = smem;            // [2][2][256*32] = 32768 elems
  ushort_t* sB = smem + 32768;

  int fid = blockIdx.x;
  bool second = fid >= split;
  GSeg s = second ? s1 : s0;
  int lid = second ? fid - split : fid;
  // T1: chunked bijective XCD swizzle (nblk divisible by 8 for all segments)
  int cpx = s.nblk >> 3;
  int swz = (lid & 7) * cpx + (lid >> 3);
  int x = swz % s.gx;
  int t = swz / s.gx;
  int y = t % s.gy;
  int b = t / s.gy;

  int m0 = x * 256, n0 = y * 256;
  const ushort_t* Ab = s.A + ((size_t)b * s.M + m0) * s.K;
  const ushort_t* Bb = s.BT + ((size_t)b * s.N + n0) * s.K;
  int tid = threadIdx.x;
  int l = tid & 63, w = tid >> 6;
  int wm = w >> 2, wn = w & 3;          // wave tile: rows wm*128, cols wn*64
  int low = l & 15, quad = l >> 4;
  // read-side st_16x32 swizzle folds to a per-lane col XOR (frag row bit3 = l&8)
  const int colsw = (quad * 8) ^ ((l & 8) ? 16 : 0);
  const int K = s.K;
  int NT = K >> 6;  // K-tiles of 64

  f32x4 acc[8][4];
  f32x4 zero = {0.f, 0.f, 0.f, 0.f};
#pragma unroll
  for (int i = 0; i < 8; ++i)
#pragma unroll
    for (int j = 0; j < 4; ++j) acc[i][j] = zero;

  // stage one K-half (256x32) of tile T into its dbuf slot. Linear LDS dest;
  // source chunk index inverse-swizzled (row&8 -> chunk^2).
  auto stageT = [&](const ushort_t* gb, ushort_t* sbase, int T, int kh) {
    ushort_t* hb = sbase + (((T & 1) << 1) + kh) * 8192;  // wave-uniform region
    int kc0 = (T << 6) + (kh << 5);
#pragma unroll
    for (int ii = 0; ii < 2; ++ii) {
      int o = w * 128 + ii * 64;  // wave-uniform chunk base (16B chunks)
      int ol = o + l;
      int cc = ((ol & 3) ^ ((l >> 4) & 2)) << 3;
      async16(gb + (size_t)(ol >> 2) * K + kc0 + cc, hb + o * 8);
    }
  };
  auto ldA = [&](bf16x8 (&af)[4], int buf, int k, int h) {
    const ushort_t* base = sA + ((buf << 1) + k) * 8192 + colsw;
    int r0 = wm * 128 + h * 64 + low;
#pragma unroll
    for (int i = 0; i < 4; ++i) af[i] = *(const bf16x8*)&base[(r0 + i * 16) * 32];
  };
  auto ldB = [&](bf16x8 (&bfv)[4], int buf, int k) {
    const ushort_t* base = sB + ((buf << 1) + k) * 8192 + colsw;
    int r0 = wn * 64 + low;
#pragma unroll
    for (int j = 0; j < 4; ++j) bfv[j] = *(const bf16x8*)&base[(r0 + j * 16) * 32];
  };

  // ---- prologue: tile0 (4 halves) + tile1 minus A-K1 (staged at ph1 of T=0)
  stageT(Ab, sA, 0, 0);
  stageT(Bb, sB, 0, 0);
  stageT(Ab, sA, 0, 1);
  stageT(Bb, sB, 0, 1);
  VMCNT(4);
  if (NT > 1) {
    stageT(Bb, sB, 1, 0);
    stageT(Ab, sA, 1, 0);
    stageT(Bb, sB, 1, 1);
    VMCNT(6);   // 14 issued/wave, <=6 outstanding => tile0's 8 landed
  } else {
    VMCNT(0);
  }
  BARRIER();

  bf16x8 af[4], bfv[4];
  for (int T = 0; T < NT; ++T) {
    int buf = T & 1;
    // ph1 (k0,h0). Stage A-K1(T+1) -> buf^1 (region sealed at ph4(T-1)).
    ldB(bfv, buf, 0);
    ldA(af, buf, 0, 0);
    if (T + 1 < NT) stageT(Ab, sA, T + 1, 1);
    BARRIER();
    mm8<0>(acc, af, bfv);
    BARRIER();
    // ph2 (k0,h1): last reader of A-K0(T). Stage B-K0(T+2) (sealed @ph1).
    ldA(af, buf, 0, 1);
    if (T + 2 < NT) stageT(Bb, sB, T + 2, 0);
    BARRIER();
    mm8<1>(acc, af, bfv);
    BARRIER();
    // ph3 (k1,h0). Stage A-K0(T+2) (sealed @ph2).
    ldB(bfv, buf, 1);
    ldA(af, buf, 1, 0);
    if (T + 2 < NT) stageT(Ab, sA, T + 2, 0);
    BARRIER();
    mm8<0>(acc, af, bfv);
    BARRIER();
    // ph4 (k1,h1): last reader of tile T. Stage B-K1(T+2) (sealed @ph3).
    // vmcnt(6): newest-3 halves are tile T+2's => tile T+1 fully landed.
    ldA(af, buf, 1, 1);
    if (T + 2 < NT) stageT(Bb, sB, T + 2, 1);
    if (T + 1 < NT) {
      if (T + 2 < NT) { VMCNT(6); } else { VMCNT(0); }  // tail drain
    }
    BARRIER();
    mm8<1>(acc, af, bfv);
    BARRIER();
  }

  // ---- epilogue (runtime mode; uniform branches)
  size_t ob = (size_t)b * s.M * s.N;
  if (s.mode == 2) {
    const float sc = 0.04419417382415922f;  // 1/sqrt(512)
#pragma unroll
    for (int i = 0; i < 8; ++i) {
      int gr0 = m0 + wm * 128 + i * 16 + quad * 4;
#pragma unroll
      for (int r = 0; r < 4; ++r) {
        int gr = gr0 + r;
        float rs = 0.f;
#pragma unroll
        for (int j = 0; j < 4; ++j) {
          float p = __expf(acc[i][j][r] * sc);  // |scores| small: no max-sub
          rs += p;
          int gc = n0 + wn * 64 + j * 16 + low;
          s.outB[ob + (size_t)gr * s.N + gc] = f2bf(p);
        }
        rs += __shfl_xor(rs, 1);
        rs += __shfl_xor(rs, 2);
        rs += __shfl_xor(rs, 4);
        rs += __shfl_xor(rs, 8);
        if (low == 0) atomicAdd(&s.lsumOut[(size_t)b * s.M + gr], rs);
      }
    }
  } else {
#pragma unroll
    for (int i = 0; i < 8; ++i) {
      int gr0 = m0 + wm * 128 + i * 16 + quad * 4;
#pragma unroll
      for (int r = 0; r < 4; ++r) {
        int gr = gr0 + r;
        float inv = 1.f;
        if (s.lsumIn) inv = 1.f / s.lsumIn[(size_t)b * s.M + gr];
#pragma unroll
        for (int j = 0; j < 4; ++j) {
          int gc = n0 + wn * 64 + j * 16 + low;
          float o = acc[i][j][r] * inv;
          s.outF[ob + (size_t)gr * s.N + gc] = o;
          if (s.outB) s.outB[ob + (size_t)gr * s.N + gc] = f2bf(o);
        }
      }
    }
  }
}

#define LDS_BYTES 131072

extern "C" void kernel_launch(void* const* d_in, const int* in_sizes, int n_in,
                              void* d_out, int out_size, void* d_ws, size_t ws_size,
                              hipStream_t stream) {
  (void)in_sizes; (void)n_in; (void)out_size; (void)ws_size;
  const float* pre = (const float*)d_in[0];
  const float* q   = (const float*)d_in[1];
  const float* v   = (const float*)d_in[2];

  float* out      = (float*)d_out;
  float* wc       = out;                                   // weightedContext [B][LQ][DIM]
  float* energy   = out + (size_t)BATCH * LQ * DIM;        // energy          [B][LQ][DIM]
  float* precomp  = out + 2 * (size_t)BATCH * LQ * DIM;    // precompute      [B][LP][DIM]

  char* ws = (char*)d_ws;
  size_t off = 0;
  auto alloc = [&](size_t bytes) {
    void* p = ws + off;
    off += (bytes + 255) & ~(size_t)255;
    return p;
  };
  ushort_t* preB = (ushort_t*)alloc((size_t)BATCH * LP * DIM * 2);
  ushort_t* qB   = (ushort_t*)alloc((size_t)BATCH * LQ * DIM * 2);
  ushort_t* vB   = (ushort_t*)alloc((size_t)BATCH * LV * DIM * 2);
  ushort_t* qT   = (ushort_t*)alloc((size_t)BATCH * DIM * LQ * 2);
  ushort_t* vT   = (ushort_t*)alloc((size_t)BATCH * DIM * LV * 2);
  ushort_t* Pp   = (ushort_t*)alloc((size_t)BATCH * LP * LQ * 2);
  ushort_t* Pe   = (ushort_t*)alloc((size_t)BATCH * LQ * LV * 2);
  ushort_t* Ebf  = (ushort_t*)alloc((size_t)BATCH * LQ * DIM * 2);
  float* lp = (float*)alloc((size_t)BATCH * LP * 4);   // 128 KiB, 256-aligned
  float* le = (float*)alloc((size_t)BATCH * LQ * 4);   // contiguous after lp

  static bool attr_done = false;
  if (!attr_done) {
    attr_done = true;
    hipFuncSetAttribute(reinterpret_cast<const void*>(&gemm256d),
                        hipFuncAttributeMaxDynamicSharedMemorySize, LDS_BYTES);
  }

  // prep: one launch (pre cvt + lp/le zero + q/v transpose-cvt)
  prep_kernel<<<8192 + 64 + 4096 + 2048, 256, 0, stream>>>(
      pre, q, v, preB, qB, vB, qT, vT, lp);

  // scores: Pp = exp(sc*pre.q^T) [B][LP][LQ]; Pe = exp(sc*q.v^T) [B][LQ][LV]
  GSeg sc1 = {preB, qB, nullptr, nullptr, Pp, lp, LP, LQ, DIM, LP / 256, LQ / 256,
              (LP / 256) * (LQ / 256) * BATCH, 2};
  GSeg sc2 = {qB, vB, nullptr, nullptr, Pe, le, LQ, LV, DIM, LQ / 256, LV / 256,
              (LQ / 256) * (LV / 256) * BATCH, 2};
  gemm256d<<<sc1.nblk + sc2.nblk, 512, LDS_BYTES, stream>>>(sc1, sc2, sc1.nblk);

  // pv: precompute = (Pp.q)/lp ; energy = (Pe.v)/le (+bf16 copy Ebf)
  GSeg pv1 = {Pp, qT, lp, precomp, nullptr, nullptr, LP, DIM, LQ, LP / 256, DIM / 256,
              (LP / 256) * (DIM / 256) * BATCH, 1};
  GSeg pv2 = {Pe, vT, le, energy, Ebf, nullptr, LQ, DIM, LV, LQ / 256, DIM / 256,
              (LQ / 256) * (DIM / 256) * BATCH, 1};
  gemm256d<<<pv1.nblk + pv2.nblk, 512, LDS_BYTES, stream>>>(pv1, pv2, pv1.nblk);

  // weightedContext = Ebf . v
  GSeg wcs = {Ebf, vT, nullptr, wc, nullptr, nullptr, LQ, DIM, LV, LQ / 256, DIM / 256,
              (LQ / 256) * (DIM / 256) * BATCH, 0};
  gemm256d<<<wcs.nblk, 512, LDS_BYTES, stream>>>(wcs, wcs, wcs.nblk);
}